// Round 1
// 438.716 us; speedup vs baseline: 1.0216x; 1.0216x over previous
//
#include <hip/hip_runtime.h>

// Problem constants (from reference setup_inputs):
//   x: (B=4, S=8192, D=2048) fp32, w: (D, 1, K=4) fp32, out: (B, S, D) fp32
//   y[b,s,d] = silu( sum_k x[b, s-3+k, d] * w[d,0,k] )   (causal left-pad 3)
constexpr int B = 4;
constexpr int S = 8192;
constexpr int D = 2048;
constexpr int K = 4;

constexpr int T     = 64;    // consecutive s-values per thread (halo = 3/64 = 4.7%)
constexpr int CH    = 8;     // rows per load-batch chunk (8 x float4 = 32 VGPR of data)
constexpr int BLOCK = 256;   // threads per block; each thread owns 4 d-channels

__device__ __forceinline__ float fsilu(float v) {
    // silu(v) = v * sigmoid(v); fast rcp instead of precise v_div_* expansion.
    return v * __builtin_amdgcn_rcpf(1.f + __expf(-v));
}

__global__ __launch_bounds__(BLOCK)
void causal_conv1d_silu(const float* __restrict__ x,
                        const float* __restrict__ w,
                        float* __restrict__ out) {
    // grid: (S/T, D/(BLOCK*4), B) = (128, 2, 4) -> 1024 blocks = 4 blocks/CU
    const int tid = threadIdx.x;
    const int d   = (blockIdx.y * BLOCK + tid) * 4;   // first of 4 d-channels
    const int b   = blockIdx.z;
    const int s0  = blockIdx.x * T;

    // Weights for d..d+3: w[(d+j)*K + k], 16 contiguous floats, 16B aligned.
    const float4* w4 = reinterpret_cast<const float4*>(w + (size_t)d * K);
    const float4 wd0 = w4[0];  // weights (k=0..3) for channel d+0
    const float4 wd1 = w4[1];
    const float4 wd2 = w4[2];
    const float4 wd3 = w4[3];

    const float* xp = x   + (size_t)b * S * D + d;
    float*       op = out + (size_t)b * S * D + d;

    const float4 zero = make_float4(0.f, 0.f, 0.f, 0.f);
    // Sliding window: x3 = x[s-3], x2 = x[s-2], x1 = x[s-1]
    float4 x3 = (s0 >= 3) ? *reinterpret_cast<const float4*>(xp + (size_t)(s0 - 3) * D) : zero;
    float4 x2 = (s0 >= 2) ? *reinterpret_cast<const float4*>(xp + (size_t)(s0 - 2) * D) : zero;
    float4 x1 = (s0 >= 1) ? *reinterpret_cast<const float4*>(xp + (size_t)(s0 - 1) * D) : zero;

    for (int c = 0; c < T / CH; ++c) {
        const int sbase = s0 + c * CH;

        // Batch the 8 independent row loads so they all go in flight together
        // (one vmcnt group), instead of load/compute/store interleave per row.
        float4 xv[CH];
#pragma unroll
        for (int j = 0; j < CH; ++j) {
            xv[j] = *reinterpret_cast<const float4*>(xp + (size_t)(sbase + j) * D);
        }

#pragma unroll
        for (int j = 0; j < CH; ++j) {
            const float4 x0 = xv[j];
            float4 y;
            y.x = wd0.x * x3.x + wd0.y * x2.x + wd0.z * x1.x + wd0.w * x0.x;
            y.y = wd1.x * x3.y + wd1.y * x2.y + wd1.z * x1.y + wd1.w * x0.y;
            y.z = wd2.x * x3.z + wd2.y * x2.z + wd2.z * x1.z + wd2.w * x0.z;
            y.w = wd3.x * x3.w + wd3.y * x2.w + wd3.z * x1.w + wd3.w * x0.w;

            y.x = fsilu(y.x);
            y.y = fsilu(y.y);
            y.z = fsilu(y.z);
            y.w = fsilu(y.w);

            *reinterpret_cast<float4*>(op + (size_t)(sbase + j) * D) = y;

            x3 = x2; x2 = x1; x1 = x0;
        }
    }
}

extern "C" void kernel_launch(void* const* d_in, const int* in_sizes, int n_in,
                              void* d_out, int out_size, void* d_ws, size_t ws_size,
                              hipStream_t stream) {
    const float* x = (const float*)d_in[0];
    const float* w = (const float*)d_in[1];
    float* out = (float*)d_out;

    dim3 grid(S / T, D / (BLOCK * 4), B);
    dim3 block(BLOCK);
    causal_conv1d_silu<<<grid, block, 0, stream>>>(x, w, out);
}